// Round 1
// baseline (435.540 us; speedup 1.0000x reference)
//
#include <hip/hip_runtime.h>

static constexpr int B = 256;  // BATCH in reference

// ---------------------------------------------------------------------------
// Build child-offset arrays for all 3 levels from flat_idx arrays.
// flat_idx[k] = i*M + j  (i = parent slot, j = child col). j==0 marks the
// start of parent i's children in concat order. offs[P] = n.
// M is a device-resident scalar (single-element int input).
// ---------------------------------------------------------------------------
__global__ void build_offs3(
    const int* __restrict__ f0, int n0, const int* __restrict__ M0p, int P0, int* __restrict__ offs0,
    const int* __restrict__ f1, int n1, const int* __restrict__ M1p, int P1, int* __restrict__ offs1,
    const int* __restrict__ f2, int n2, const int* __restrict__ M2p, int P2, int* __restrict__ offs2)
{
    int k = blockIdx.x * blockDim.x + threadIdx.x;
    if (k < n0) {
        int M = M0p[0];
        int v = f0[k];
        int i = v / M;
        if (v - i * M == 0) offs0[i] = k;
    }
    if (k < n1) {
        int M = M1p[0];
        int v = f1[k];
        int i = v / M;
        if (v - i * M == 0) offs1[i] = k;
    }
    if (k < n2) {
        int M = M2p[0];
        int v = f2[k];
        int i = v / M;
        if (v - i * M == 0) offs2[i] = k;
    }
    if (k == 0) { offs0[P0] = n0; offs1[P1] = n1; offs2[P2] = n2; }
}

// ---------------------------------------------------------------------------
// One wave (64 lanes) per (parent slot, batch).
// COPY=true: children are leaves; read from scores and also copy them to out
//            (this is the only pass that writes the leaf region of out).
// COPY=false: children were updated by a previous dispatch; read from out.
// In both cases the parent's base value comes from scores (reference semantics:
// parent entries are untouched by deeper levels before their own update).
// out[b][parent] = max(scores[b][parent], logsumexp(children)).
// ---------------------------------------------------------------------------
template <bool COPY>
__global__ void __launch_bounds__(256) level_reduce(
    const float* __restrict__ scores, float* __restrict__ out,
    const int* __restrict__ offs,
    const int* __restrict__ pbase_p,  // parent node ids (arange) — read [0]
    const int* __restrict__ cbase_p,  // concat child node ids (arange) — read [0]
    int P, int num_nodes)
{
    const int wid  = (int)(((size_t)blockIdx.x * blockDim.x + threadIdx.x) >> 6);
    const int lane = threadIdx.x & 63;
    if (wid >= P * B) return;
    const int i = wid % P;   // parent slot — consecutive waves stream adjacent memory
    const int b = wid / P;

    const int cbase = cbase_p[0];        // first child node id (children contiguous)
    const int pnode = pbase_p[0] + i;    // parent node id
    const int s   = offs[i];
    const int cnt = offs[i + 1] - s;

    const size_t row = (size_t)b * num_nodes;
    const float* __restrict__ src = (COPY ? scores : out) + row + cbase + s;
    float*       __restrict__ dst = out + row + cbase + s;

    // online per-lane (max, sum-of-exp) — use -3e38 (finite) so empty lanes
    // never produce 0*NaN in the combine
    float m = -3.0e38f, ss = 0.0f;
    for (int k = lane; k < cnt; k += 64) {
        float x = src[k];
        if (COPY) dst[k] = x;  // leaf copy fused with the reduction read
        float nm = fmaxf(m, x);
        ss = ss * __expf(m - nm) + __expf(x - nm);
        m = nm;
    }
    // wave butterfly combine of (m, ss) pairs
#pragma unroll
    for (int off = 32; off; off >>= 1) {
        float om = __shfl_xor(m, off);
        float os = __shfl_xor(ss, off);
        float nm = fmaxf(m, om);
        ss = ss * __expf(m - nm) + os * __expf(om - nm);
        m = nm;
    }
    if (lane == 0) {
        float lse = m + __logf(ss);
        out[row + pnode] = fmaxf(scores[row + pnode], lse);
    }
}

static inline int waves_to_blocks(long long waves) {
    return (int)((waves * 64 + 255) / 256);
}

extern "C" void kernel_launch(void* const* d_in, const int* in_sizes, int n_in,
                              void* d_out, int out_size, void* d_ws, size_t ws_size,
                              hipStream_t stream) {
    // setup_inputs() order: scores, then per level d: p{d}, f{d}, c{d}, P{d}, M{d}
    const float* scores = (const float*)d_in[0];
    const int* p0 = (const int*)d_in[1];
    const int* f0 = (const int*)d_in[2];
    const int* c0 = (const int*)d_in[3];
    const int* M0 = (const int*)d_in[5];
    const int* p1 = (const int*)d_in[6];
    const int* f1 = (const int*)d_in[7];
    const int* c1 = (const int*)d_in[8];
    const int* M1 = (const int*)d_in[10];
    const int* p2 = (const int*)d_in[11];
    const int* f2 = (const int*)d_in[12];
    const int* c2 = (const int*)d_in[13];
    const int* M2 = (const int*)d_in[15];
    float* out = (float*)d_out;

    const int n0 = in_sizes[2];     // children count, level 0 (= L1)
    const int n1 = in_sizes[7];     // level 1 (= L2)
    const int n2 = in_sizes[12];    // level 2 (= L3, leaves)
    const int P0v = in_sizes[1];    // = 1
    const int P1v = in_sizes[6];    // = 100
    const int P2v = in_sizes[11];   // ~2750
    const int num_nodes = out_size / B;

    // workspace layout: three offs arrays (rebuilt every call; d_ws is poisoned)
    int* offs0 = (int*)d_ws;            // P0v+1
    int* offs1 = offs0 + (P0v + 2);     // P1v+1
    int* offs2 = offs1 + (P1v + 2);     // P2v+1

    int nmax = n2 > n1 ? n2 : n1;
    if (n0 > nmax) nmax = n0;
    build_offs3<<<(nmax + 255) / 256, 256, 0, stream>>>(
        f0, n0, M0, P0v, offs0,
        f1, n1, M1, P1v, offs1,
        f2, n2, M2, P2v, offs2);

    // deepest level first: fused leaf-copy + LSE, then level 1, then level 0
    level_reduce<true ><<<waves_to_blocks((long long)P2v * B), 256, 0, stream>>>(
        scores, out, offs2, p2, c2, P2v, num_nodes);
    level_reduce<false><<<waves_to_blocks((long long)P1v * B), 256, 0, stream>>>(
        scores, out, offs1, p1, c1, P1v, num_nodes);
    level_reduce<false><<<waves_to_blocks((long long)P0v * B), 256, 0, stream>>>(
        scores, out, offs0, p0, c0, P0v, num_nodes);
}

// Round 3
// 429.576 us; speedup vs baseline: 1.0139x; 1.0139x over previous
//
#include <hip/hip_runtime.h>

static constexpr int B = 256;  // BATCH in reference

// ---------------------------------------------------------------------------
// Build child-offset arrays for all 3 levels from flat_idx arrays.
// flat_idx[k] = i*M + j  (i = parent slot, j = col). j==0 marks the start of
// parent i's children. offs[P] = n. M is a device-resident 1-elem int array.
// ---------------------------------------------------------------------------
__global__ void build_offs3(
    const int* __restrict__ f0, int n0, const int* __restrict__ M0p, int P0, int* __restrict__ offs0,
    const int* __restrict__ f1, int n1, const int* __restrict__ M1p, int P1, int* __restrict__ offs1,
    const int* __restrict__ f2, int n2, const int* __restrict__ M2p, int P2, int* __restrict__ offs2)
{
    int k = blockIdx.x * blockDim.x + threadIdx.x;
    if (k < n0) {
        int M = M0p[0];
        int v = f0[k];
        int i = v / M;
        if (v - i * M == 0) offs0[i] = k;
    }
    if (k < n1) {
        int M = M1p[0];
        int v = f1[k];
        int i = v / M;
        if (v - i * M == 0) offs1[i] = k;
    }
    if (k < n2) {
        int M = M2p[0];
        int v = f2[k];
        int i = v / M;
        if (v - i * M == 0) offs2[i] = k;
    }
    if (k == 0) { offs0[P0] = n0; offs1[P1] = n1; offs2[P2] = n2; }
}

// ---------------------------------------------------------------------------
// One wave per (parent slot, batch). cnt <= 128 guaranteed by construction
// (M2=60, M1=50, M0=100), so each lane holds at most 2 children in registers.
// Two-phase reduction: butterfly max, ONE exp per lane, butterfly sum.
// COPY=true additionally copies the (leaf) children from scores into out —
// the only pass that writes the leaf region.
// ---------------------------------------------------------------------------
template <bool COPY>
__global__ void __launch_bounds__(256) level_reduce(
    const float* __restrict__ scores, float* __restrict__ out,
    const int* __restrict__ offs,
    const int* __restrict__ pbase_p,  // parent node ids (arange) — read [0]
    const int* __restrict__ cbase_p,  // concat child node ids (arange) — read [0]
    int P, int num_nodes)
{
    const int wid  = (int)(((long long)blockIdx.x * blockDim.x + threadIdx.x) >> 6);
    const int lane = threadIdx.x & 63;
    if (wid >= P * B) return;
    const int i = wid % P;   // consecutive waves -> adjacent segments, same row
    const int b = wid / P;

    const int cbase = cbase_p[0];
    const int pnode = pbase_p[0] + i;
    const int s   = offs[i];
    const int cnt = offs[i + 1] - s;

    const size_t row = (size_t)b * num_nodes;
    const float* __restrict__ src = (COPY ? scores : out) + row + cbase + s;
    float*       __restrict__ dst = out + row + cbase + s;

    const float NEG = -3.0e38f;  // finite stand-in for -inf: exp(NEG-m) == 0
    float x0 = NEG, x1 = NEG;
    if (lane < cnt) {
        x0 = src[lane];
        if (COPY) dst[lane] = x0;          // fused leaf copy
    }
    if (lane + 64 < cnt) {                  // only the root level (cnt=100)
        x1 = src[lane + 64];
        if (COPY) dst[lane + 64] = x1;
    }

    float m = fmaxf(x0, x1);
#pragma unroll
    for (int off = 32; off; off >>= 1)
        m = fmaxf(m, __shfl_xor(m, off));

    float e = __expf(x0 - m);               // inactive lanes: exp(-huge) = 0
    if (cnt > 64)                           // wave-uniform branch
        e += __expf(x1 - m);
#pragma unroll
    for (int off = 32; off; off >>= 1)
        e += __shfl_xor(e, off);

    if (lane == 0) {
        float lse = m + __logf(e);
        out[row + pnode] = fmaxf(scores[row + pnode], lse);
    }
}

static inline int waves_to_blocks(long long waves) {
    return (int)((waves * 64 + 255) / 256);
}

extern "C" void kernel_launch(void* const* d_in, const int* in_sizes, int n_in,
                              void* d_out, int out_size, void* d_ws, size_t ws_size,
                              hipStream_t stream) {
    // setup_inputs() order: scores, then per level d: p{d}, f{d}, c{d}, P{d}, M{d}
    const float* scores = (const float*)d_in[0];
    const int* p0 = (const int*)d_in[1];
    const int* f0 = (const int*)d_in[2];
    const int* M0 = (const int*)d_in[5];
    const int* p1 = (const int*)d_in[6];
    const int* f1 = (const int*)d_in[7];
    const int* M1 = (const int*)d_in[10];
    const int* p2 = (const int*)d_in[11];
    const int* f2 = (const int*)d_in[12];
    const int* M2 = (const int*)d_in[15];
    const int* c0 = (const int*)d_in[3];
    const int* c1 = (const int*)d_in[8];
    const int* c2 = (const int*)d_in[13];
    float* out = (float*)d_out;

    const int n0 = in_sizes[2];     // total children, level 0
    const int n1 = in_sizes[7];     // level 1
    const int n2 = in_sizes[12];    // level 2 (leaves)
    const int P0v = in_sizes[1];    // = 1
    const int P1v = in_sizes[6];    // = 100
    const int P2v = in_sizes[11];   // ~2750
    const int num_nodes = out_size / B;

    int* offs0 = (int*)d_ws;            // P0v+1
    int* offs1 = offs0 + (P0v + 2);     // P1v+1
    int* offs2 = offs1 + (P1v + 2);     // P2v+1

    int nmax = n2 > n1 ? n2 : n1;
    if (n0 > nmax) nmax = n0;
    build_offs3<<<(nmax + 255) / 256, 256, 0, stream>>>(
        f0, n0, M0, P0v, offs0,
        f1, n1, M1, P1v, offs1,
        f2, n2, M2, P2v, offs2);

    level_reduce<true ><<<waves_to_blocks((long long)P2v * B), 256, 0, stream>>>(
        scores, out, offs2, p2, c2, P2v, num_nodes);
    level_reduce<false><<<waves_to_blocks((long long)P1v * B), 256, 0, stream>>>(
        scores, out, offs1, p1, c1, P1v, num_nodes);
    level_reduce<false><<<waves_to_blocks((long long)P0v * B), 256, 0, stream>>>(
        scores, out, offs0, p0, c0, P0v, num_nodes);
}

// Round 5
// 266.339 us; speedup vs baseline: 1.6353x; 1.6129x over previous
//
#include <hip/hip_runtime.h>

static constexpr int B = 256;  // BATCH in reference

// ---------------------------------------------------------------------------
// Build child-offset arrays for all 3 levels from flat_idx arrays.
// flat_idx[k] = i*M + j; j==0 marks the start of parent i's children.
// offs[P] = n. M is a device-resident 1-elem int array.
// ---------------------------------------------------------------------------
__global__ void build_offs3(
    const int* __restrict__ f0, int n0, const int* __restrict__ M0p, int P0, int* __restrict__ offs0,
    const int* __restrict__ f1, int n1, const int* __restrict__ M1p, int P1, int* __restrict__ offs1,
    const int* __restrict__ f2, int n2, const int* __restrict__ M2p, int P2, int* __restrict__ offs2)
{
    int k = blockIdx.x * blockDim.x + threadIdx.x;
    if (k < n0) {
        int M = M0p[0];
        int v = f0[k];
        int i = v / M;
        if (v - i * M == 0) offs0[i] = k;
    }
    if (k < n1) {
        int M = M1p[0];
        int v = f1[k];
        int i = v / M;
        if (v - i * M == 0) offs1[i] = k;
    }
    if (k < n2) {
        int M = M2p[0];
        int v = f2[k];
        int i = v / M;
        if (v - i * M == 0) offs2[i] = k;
    }
    if (k == 0) { offs0[P0] = n0; offs1[P1] = n1; offs2[P2] = n2; }
}

// ---------------------------------------------------------------------------
// Chunked LDS-staged segmented logsumexp.
// Grid: (ceil(P/PPB), B). Block: 256 threads, PPB=64 parents per block.
// Phase 1: stream the block's contiguous child span into LDS, coalesced
//          (COPY=true also writes it to out — the fused leaf copy).
// Phase 2: 4 threads per parent reduce the segment from LDS (stride-4),
//          combine via 2 shuffles, lane q==0 writes
//          out[parent] = max(scores[parent], m + log(sum)).
// Max span: leaf 64*60=3840, level1 64*50, level0 100 -> 15.4 KB LDS.
// ---------------------------------------------------------------------------
template <bool COPY>
__global__ void __launch_bounds__(256) level_reduce_chunk(
    const float* __restrict__ scores, float* __restrict__ out,
    const int* __restrict__ offs,
    const int* __restrict__ pbase_p,  // parent node ids (arange) — read [0]
    const int* __restrict__ cbase_p,  // concat child node ids (arange) — read [0]
    int P, int num_nodes)
{
    constexpr int PPB = 64;
    constexpr int MAXSPAN = PPB * 60;
    __shared__ float vals[MAXSPAN];

    const int tid  = threadIdx.x;
    const int p0   = blockIdx.x * PPB;
    const int pcnt = min(PPB, P - p0);
    const int b    = blockIdx.y;

    const int cbase = cbase_p[0];
    const int pbase = pbase_p[0];
    const int e0 = offs[p0];
    const int e1 = offs[p0 + pcnt];
    const int span = e1 - e0;

    const size_t row = (size_t)b * num_nodes;
    const float* __restrict__ src  = (COPY ? scores : out) + row + cbase + e0;
    float*       __restrict__ dstc = out + row + cbase + e0;

    for (int k = tid; k < span; k += 256) {
        float v = src[k];
        if (COPY) dstc[k] = v;   // fused leaf copy (only writer of leaf region)
        vals[k] = v;
    }
    __syncthreads();

    const int p = tid >> 2;   // 4 threads per parent; group within one wave
    const int q = tid & 3;
    if (p < pcnt) {
        const int sa  = offs[p0 + p];
        const int cnt = offs[p0 + p + 1] - sa;
        const int s   = sa - e0;
        const float NEG = -3.0e38f;   // finite -inf stand-in
        float m = NEG;
        for (int k = q; k < cnt; k += 4) m = fmaxf(m, vals[s + k]);
        m = fmaxf(m, __shfl_xor(m, 1));
        m = fmaxf(m, __shfl_xor(m, 2));
        float e = 0.0f;
        for (int k = q; k < cnt; k += 4) e += __expf(vals[s + k] - m);
        e += __shfl_xor(e, 1);
        e += __shfl_xor(e, 2);
        if (q == 0) {
            const int pnode = pbase + p0 + p;   // parents contiguous -> coalesced
            float lse = m + __logf(e);
            out[row + pnode] = fmaxf(scores[row + pnode], lse);
        }
    }
}

extern "C" void kernel_launch(void* const* d_in, const int* in_sizes, int n_in,
                              void* d_out, int out_size, void* d_ws, size_t ws_size,
                              hipStream_t stream) {
    // setup_inputs() order: scores, then per level d: p{d}, f{d}, c{d}, P{d}, M{d}
    const float* scores = (const float*)d_in[0];
    const int* p0 = (const int*)d_in[1];
    const int* f0 = (const int*)d_in[2];
    const int* M0 = (const int*)d_in[5];
    const int* p1 = (const int*)d_in[6];
    const int* f1 = (const int*)d_in[7];
    const int* M1 = (const int*)d_in[10];
    const int* p2 = (const int*)d_in[11];
    const int* f2 = (const int*)d_in[12];
    const int* M2 = (const int*)d_in[15];
    const int* c0 = (const int*)d_in[3];
    const int* c1 = (const int*)d_in[8];
    const int* c2 = (const int*)d_in[13];
    float* out = (float*)d_out;

    const int n0 = in_sizes[2];     // total children, level 0
    const int n1 = in_sizes[7];     // level 1
    const int n2 = in_sizes[12];    // level 2 (leaves)
    const int P0v = in_sizes[1];    // = 1
    const int P1v = in_sizes[6];    // = 100
    const int P2v = in_sizes[11];   // ~2750
    const int num_nodes = out_size / B;

    int* offs0 = (int*)d_ws;            // P0v+1
    int* offs1 = offs0 + (P0v + 2);     // P1v+1
    int* offs2 = offs1 + (P1v + 2);     // P2v+1

    int nmax = n2 > n1 ? n2 : n1;
    if (n0 > nmax) nmax = n0;
    build_offs3<<<(nmax + 255) / 256, 256, 0, stream>>>(
        f0, n0, M0, P0v, offs0,
        f1, n1, M1, P1v, offs1,
        f2, n2, M2, P2v, offs2);

    constexpr int PPB = 64;
    dim3 g2((P2v + PPB - 1) / PPB, B);
    dim3 g1((P1v + PPB - 1) / PPB, B);
    dim3 g0((P0v + PPB - 1) / PPB, B);
    level_reduce_chunk<true ><<<g2, 256, 0, stream>>>(scores, out, offs2, p2, c2, P2v, num_nodes);
    level_reduce_chunk<false><<<g1, 256, 0, stream>>>(scores, out, offs1, p1, c1, P1v, num_nodes);
    level_reduce_chunk<false><<<g0, 256, 0, stream>>>(scores, out, offs0, p0, c0, P0v, num_nodes);
}

// Round 6
// 257.938 us; speedup vs baseline: 1.6885x; 1.0326x over previous
//
#include <hip/hip_runtime.h>

static constexpr int B = 256;  // BATCH in reference

// ---------------------------------------------------------------------------
// Build child-offset arrays for all 3 levels from flat_idx arrays.
// flat_idx[k] = i*M + j; j==0 marks the start of parent i's children.
// offs[P] = n. M is a device-resident 1-elem int array.
// ---------------------------------------------------------------------------
__global__ void build_offs3(
    const int* __restrict__ f0, int n0, const int* __restrict__ M0p, int P0, int* __restrict__ offs0,
    const int* __restrict__ f1, int n1, const int* __restrict__ M1p, int P1, int* __restrict__ offs1,
    const int* __restrict__ f2, int n2, const int* __restrict__ M2p, int P2, int* __restrict__ offs2)
{
    int k = blockIdx.x * blockDim.x + threadIdx.x;
    if (k < n0) {
        int M = M0p[0];
        int v = f0[k];
        int i = v / M;
        if (v - i * M == 0) offs0[i] = k;
    }
    if (k < n1) {
        int M = M1p[0];
        int v = f1[k];
        int i = v / M;
        if (v - i * M == 0) offs1[i] = k;
    }
    if (k < n2) {
        int M = M2p[0];
        int v = f2[k];
        int i = v / M;
        if (v - i * M == 0) offs2[i] = k;
    }
    if (k == 0) { offs0[P0] = n0; offs1[P1] = n1; offs2[P2] = n2; }
}

// ---------------------------------------------------------------------------
// Leaf kernel: PPB=64 parents per block, grid (ceil(P/PPB), B).
// Stage the block's contiguous child span with float4 (scalar prologue to a
// 16B boundary in global-index space; LDS shifted by `pad` so LDS quads stay
// aligned), fused leaf copy to out. Then 4 threads/parent reduce from a
// register cache x[15] (one LDS read per element, statically indexed).
// Segment cnt <= M2 = 60 -> ceil(60/4) = 15 iterations.
// ---------------------------------------------------------------------------
__global__ void __launch_bounds__(256) leaf_reduce(
    const float* __restrict__ scores, float* __restrict__ out,
    const int* __restrict__ offs,
    const int* __restrict__ pbase_p, const int* __restrict__ cbase_p,
    int P, int num_nodes)
{
    constexpr int PPB = 64;
    constexpr int MAXSPAN = PPB * 60;
    __shared__ __align__(16) float vals[MAXSPAN + 8];

    const int tid  = threadIdx.x;
    const int p0   = blockIdx.x * PPB;
    const int pcnt = min(PPB, P - p0);
    const int b    = blockIdx.y;

    const int cbase = cbase_p[0];
    const int pbase = pbase_p[0];
    const int e0 = offs[p0];
    const int e1 = offs[p0 + pcnt];
    const int span = e1 - e0;

    const size_t row = (size_t)b * num_nodes;
    const size_t g0  = row + cbase + e0;           // global flat idx of span start
    const float* __restrict__ src = scores + g0;
    float*       __restrict__ dst = out + g0;

    const int a   = (int)((4 - (g0 & 3)) & 3);     // elems until 16B alignment
    const int pro = a < span ? a : span;
    const int pad = (4 - a) & 3;                   // LDS shift: (pad+pro)%4==0

    if (tid < pro) { float v = src[tid]; dst[tid] = v; vals[pad + tid] = v; }
    const int nq = (span - pro) >> 2;
    const float4* __restrict__ src4 = (const float4*)(src + pro);
    float4*       __restrict__ dst4 = (float4*)(dst + pro);
    float4*                    lds4 = (float4*)(vals + pad + pro);
    for (int j = tid; j < nq; j += 256) {
        float4 v = src4[j];
        dst4[j] = v;          // fused leaf copy
        lds4[j] = v;
    }
    const int rem = span - pro - (nq << 2);        // 0..3
    if (tid < rem) {
        int k = pro + (nq << 2) + tid;
        float v = src[k]; dst[k] = v; vals[pad + k] = v;
    }
    __syncthreads();

    const int p = tid >> 2;    // 4 threads per parent, group within one wave
    const int q = tid & 3;
    if (p < pcnt) {
        const int sa  = offs[p0 + p];
        const int cnt = offs[p0 + p + 1] - sa;
        const int s   = sa - e0 + pad;
        const int hi  = span + pad - 1;
        const float NEG = -3.0e38f;
        float x[15];
#pragma unroll
        for (int k = 0; k < 15; ++k) {
            int idx = s + q + 4 * k;
            idx = idx < hi ? idx : hi;             // clamp: stay in-bounds
            float v = vals[idx];
            x[k] = (q + 4 * k < cnt) ? v : NEG;
        }
        float m = NEG;
#pragma unroll
        for (int k = 0; k < 15; ++k) m = fmaxf(m, x[k]);
        m = fmaxf(m, __shfl_xor(m, 1));
        m = fmaxf(m, __shfl_xor(m, 2));
        float e = 0.0f;
#pragma unroll
        for (int k = 0; k < 15; ++k) e += __expf(x[k] - m);
        e += __shfl_xor(e, 1);
        e += __shfl_xor(e, 2);
        if (q == 0) {
            const int pnode = pbase + p0 + p;
            float lse = m + __logf(e);
            out[row + pnode] = fmaxf(scores[row + pnode], lse);
        }
    }
}

// ---------------------------------------------------------------------------
// Upper kernel: one block per batch row; does level 1 AND level 0 (root).
// Stage out[row, c1base .. c1base+n1) (written by leaf_reduce) into LDS,
// 2 threads/parent for the P1 (=100) level-1 LSEs (cnt <= M1 = 50 -> 25
// iters), keep updated parent values in LDS, then wave 0 reduces the root
// over its n0 (=100) children (= the updated level-1 values).
// ---------------------------------------------------------------------------
__global__ void __launch_bounds__(256) upper_reduce(
    const float* __restrict__ scores, float* __restrict__ out,
    const int* __restrict__ offs1,
    const int* __restrict__ p1base_p, const int* __restrict__ c1base_p,
    const int* __restrict__ p0base_p,
    int P1, int n1, int n0, int num_nodes)
{
    __shared__ __align__(16) float vals[5128];   // n1 <= P1*M1 = 5000
    __shared__ float upd[128];

    const int tid = threadIdx.x;
    const int b   = blockIdx.x;
    const size_t row = (size_t)b * num_nodes;

    const int c1base = c1base_p[0];
    const int p1base = p1base_p[0];
    const int p0base = p0base_p[0];

    // stage level-2-parent outputs (leaf_reduce results) into LDS, float4
    const size_t g0 = row + c1base;
    const float* __restrict__ src = out + g0;
    const int a   = (int)((4 - (g0 & 3)) & 3);
    const int pro = a < n1 ? a : n1;
    const int pad = (4 - a) & 3;
    if (tid < pro) vals[pad + tid] = src[tid];
    const int nq = (n1 - pro) >> 2;
    const float4* __restrict__ src4 = (const float4*)(src + pro);
    float4*                    lds4 = (float4*)(vals + pad + pro);
    for (int j = tid; j < nq; j += 256) lds4[j] = src4[j];
    const int rem = n1 - pro - (nq << 2);
    if (tid < rem) { int k = pro + (nq << 2) + tid; vals[pad + k] = src[k]; }
    __syncthreads();

    // level 1: 2 threads per parent
    const int p = tid >> 1;
    const int q = tid & 1;
    const float NEG = -3.0e38f;
    if (p < P1) {
        const int sa  = offs1[p];
        const int cnt = offs1[p + 1] - sa;
        const int s   = sa + pad;
        float m = NEG;
        for (int k = q; k < cnt; k += 2) m = fmaxf(m, vals[s + k]);
        m = fmaxf(m, __shfl_xor(m, 1));
        float e = 0.0f;
        for (int k = q; k < cnt; k += 2) e += __expf(vals[s + k] - m);
        e += __shfl_xor(e, 1);
        if (q == 0) {
            const int pnode = p1base + p;
            float lse = m + __logf(e);
            float v = fmaxf(scores[row + pnode], lse);
            out[row + pnode] = v;
            upd[p] = v;
        }
    }
    __syncthreads();

    // level 0 (root): wave 0 reduces the n0 (=P1) updated level-1 values
    if (tid < 64) {
        float x0 = (tid      < n0) ? upd[tid]      : NEG;
        float x1 = (tid + 64 < n0) ? upd[tid + 64] : NEG;
        float m = fmaxf(x0, x1);
#pragma unroll
        for (int off = 32; off; off >>= 1) m = fmaxf(m, __shfl_xor(m, off));
        float e = __expf(x0 - m) + __expf(x1 - m);
#pragma unroll
        for (int off = 32; off; off >>= 1) e += __shfl_xor(e, off);
        if (tid == 0) {
            float lse = m + __logf(e);
            out[row + p0base] = fmaxf(scores[row + p0base], lse);
        }
    }
}

extern "C" void kernel_launch(void* const* d_in, const int* in_sizes, int n_in,
                              void* d_out, int out_size, void* d_ws, size_t ws_size,
                              hipStream_t stream) {
    // setup_inputs() order: scores, then per level d: p{d}, f{d}, c{d}, P{d}, M{d}
    const float* scores = (const float*)d_in[0];
    const int* p0 = (const int*)d_in[1];
    const int* f0 = (const int*)d_in[2];
    const int* M0 = (const int*)d_in[5];
    const int* p1 = (const int*)d_in[6];
    const int* f1 = (const int*)d_in[7];
    const int* M1 = (const int*)d_in[10];
    const int* p2 = (const int*)d_in[11];
    const int* f2 = (const int*)d_in[12];
    const int* M2 = (const int*)d_in[15];
    const int* c1 = (const int*)d_in[8];
    const int* c2 = (const int*)d_in[13];
    float* out = (float*)d_out;

    const int n0 = in_sizes[2];     // total children, level 0 (=100)
    const int n1 = in_sizes[7];     // level 1 (~2750)
    const int n2 = in_sizes[12];    // level 2 (leaves, ~110k)
    const int P0v = in_sizes[1];    // = 1
    const int P1v = in_sizes[6];    // = 100
    const int P2v = in_sizes[11];   // ~2750
    const int num_nodes = out_size / B;

    int* offs0 = (int*)d_ws;            // P0v+1
    int* offs1 = offs0 + (P0v + 2);     // P1v+1
    int* offs2 = offs1 + (P1v + 2);     // P2v+1

    int nmax = n2 > n1 ? n2 : n1;
    if (n0 > nmax) nmax = n0;
    build_offs3<<<(nmax + 255) / 256, 256, 0, stream>>>(
        f0, n0, M0, P0v, offs0,
        f1, n1, M1, P1v, offs1,
        f2, n2, M2, P2v, offs2);

    constexpr int PPB = 64;
    dim3 g2((P2v + PPB - 1) / PPB, B);
    leaf_reduce<<<g2, 256, 0, stream>>>(scores, out, offs2, p2, c2, P2v, num_nodes);
    upper_reduce<<<dim3(B), 256, 0, stream>>>(scores, out, offs1, p1, c1, p0,
                                              P1v, n1, n0, num_nodes);
}